// Round 1
// baseline (148.968 us; speedup 1.0000x reference)
//
#include <hip/hip_runtime.h>
#include <math.h>

#define BS 8
#define NPTS 8192
#define NM 32
#define D 512
#define NT (BS*NM)        // 256 total masks
#define PB 64             // point-chunks per batch
#define CPTS (NPTS/PB)    // 128 points per block

// ws layout (in floats)
// psum:   [BS*PB][NM][D]  = 8388608
// pcnt:   [BS*PB][NM]     = 16384
// avg:    [NT][D]         = 131072
// cnts:   [NT]            = 256
// logits: [NT][NT]        = 65536   -> total ~34.4 MB
static constexpr size_t OFF_PSUM = 0;
static constexpr size_t OFF_PCNT = OFF_PSUM + (size_t)BS*PB*NM*D;
static constexpr size_t OFF_AVG  = OFF_PCNT + (size_t)BS*PB*NM;
static constexpr size_t OFF_CNTS = OFF_AVG  + (size_t)NT*D;
static constexpr size_t OFF_LOG  = OFF_CNTS + (size_t)NT;

// K1: partial masked sums over a 128-point chunk of one batch.
__global__ __launch_bounds__(256) void k1_partial(const float* __restrict__ net,
                                                  const float* __restrict__ mpts,
                                                  float* __restrict__ psum,
                                                  float* __restrict__ pcnt) {
  const int blk = blockIdx.x;
  const int b  = blk >> 6;        // / PB
  const int pb = blk & (PB - 1);
  const int p0 = pb * CPTS;
  const int t  = threadIdx.x;

  // transposed mask slice: sm[p][m], row padded to 36 floats (144B = 9*16B, float4-aligned)
  __shared__ float sm[CPTS][36];
  for (int j = t; j < NM * CPTS; j += 256) {
    const int m = j >> 7;         // / CPTS
    const int p = j & (CPTS - 1);
    sm[p][m] = mpts[(((size_t)b * NM + m) << 13) + p0 + p];
  }
  __syncthreads();

  float acc[NM][2];
  #pragma unroll
  for (int m = 0; m < NM; ++m) { acc[m][0] = 0.f; acc[m][1] = 0.f; }

  // thread t owns dims 2t, 2t+1
  const float2* __restrict__ nrow =
      (const float2*)net + ((size_t)b * NPTS + p0) * (D / 2) + t;

  #pragma unroll 4
  for (int p = 0; p < CPTS; ++p) {
    const float2 v = nrow[(size_t)p * (D / 2)];
    const float4* mr = (const float4*)(&sm[p][0]);   // broadcast reads
    #pragma unroll
    for (int q = 0; q < 8; ++q) {
      const float4 mv = mr[q];
      acc[4*q+0][0] = fmaf(mv.x, v.x, acc[4*q+0][0]);
      acc[4*q+0][1] = fmaf(mv.x, v.y, acc[4*q+0][1]);
      acc[4*q+1][0] = fmaf(mv.y, v.x, acc[4*q+1][0]);
      acc[4*q+1][1] = fmaf(mv.y, v.y, acc[4*q+1][1]);
      acc[4*q+2][0] = fmaf(mv.z, v.x, acc[4*q+2][0]);
      acc[4*q+2][1] = fmaf(mv.z, v.y, acc[4*q+2][1]);
      acc[4*q+3][0] = fmaf(mv.w, v.x, acc[4*q+3][0]);
      acc[4*q+3][1] = fmaf(mv.w, v.y, acc[4*q+3][1]);
    }
  }

  float2* __restrict__ out = (float2*)(psum + (size_t)blk * NM * D) + t;
  #pragma unroll
  for (int m = 0; m < NM; ++m)
    out[(size_t)m * (D / 2)] = make_float2(acc[m][0], acc[m][1]);

  // per-block mask point counts
  if (t < NM) {
    float c = 0.f;
    #pragma unroll 8
    for (int p = 0; p < CPTS; ++p) c += sm[p][t];
    pcnt[blk * NM + t] = c;
  }
}

// K2a: reduce per-block counts -> mask_npts
__global__ __launch_bounds__(256) void k2a_counts(const float* __restrict__ pcnt,
                                                  float* __restrict__ cnts) {
  const int n = threadIdx.x;            // 0..255
  const int b = n >> 5, m = n & 31;
  float c = 0.f;
  #pragma unroll 8
  for (int pb = 0; pb < PB; ++pb) c += pcnt[(b * PB + pb) * NM + m];
  cnts[n] = c;
}

// K2b: reduce partial sums -> avg_feats
__global__ __launch_bounds__(256) void k2b_avg(const float* __restrict__ psum,
                                               const float* __restrict__ cnts,
                                               float* __restrict__ avg) {
  const int o = blockIdx.x * 256 + threadIdx.x;   // 0..131071
  const int n = o >> 9;                           // / D
  const int d = o & (D - 1);
  const int b = n >> 5, m = n & 31;
  float s = 0.f;
  #pragma unroll 8
  for (int pb = 0; pb < PB; ++pb)
    s += psum[(((size_t)(b * PB + pb) * NM + m) << 9) + d];
  avg[o] = s / (cnts[n] + 1e-12f);
}

// K3: logits[i][j] = exp(logit_scale) * dot(embs[i], avg[j])
__global__ __launch_bounds__(256) void k3_logits(const float* __restrict__ embs,
                                                 const float* __restrict__ avg,
                                                 const float* __restrict__ lsc,
                                                 float* __restrict__ logits) {
  const int i = blockIdx.x;   // row
  const int j = threadIdx.x;  // col
  __shared__ float se[D];
  for (int k = threadIdx.x; k < D; k += 256) se[k] = embs[i * D + k];
  __syncthreads();
  const float scale = expf(lsc[0]);
  const float4* __restrict__ aj = (const float4*)(avg + (size_t)j * D);
  const float4* se4 = (const float4*)se;
  float s = 0.f;
  #pragma unroll 8
  for (int k = 0; k < D / 4; ++k) {
    const float4 a = aj[k];
    const float4 e = se4[k];
    s = fmaf(e.x, a.x, s);
    s = fmaf(e.y, a.y, s);
    s = fmaf(e.z, a.z, s);
    s = fmaf(e.w, a.w, s);
  }
  logits[i * NT + j] = s * scale;
}

// K4: row/col log-softmax diagonals + nonzero-avg -> scalar loss
__global__ __launch_bounds__(256) void k4_loss(const float* __restrict__ logits,
                                               const float* __restrict__ cnts,
                                               float* __restrict__ out) {
  const int i = threadIdx.x;  // 0..255

  // row LSE (thread i reads row i; 256KB stays L2-hot)
  float mx = -1e30f;
  for (int j = 0; j < NT; ++j) mx = fmaxf(mx, logits[i * NT + j]);
  float s = 0.f;
  for (int j = 0; j < NT; ++j) s += expf(logits[i * NT + j] - mx);
  const float rowlse = mx + logf(s);

  // col LSE (coalesced)
  float mc = -1e30f;
  for (int k = 0; k < NT; ++k) mc = fmaxf(mc, logits[k * NT + i]);
  float sc = 0.f;
  for (int k = 0; k < NT; ++k) sc += expf(logits[k * NT + i] - mc);
  const float collse = mc + logf(sc);

  const float diag = logits[i * NT + i];
  const bool valid = cnts[i] > 0.f;
  const float tl = valid ? (rowlse - diag) : 0.f;
  const float pl = valid ? (collse - diag) : 0.f;

  __shared__ float red[4][256];
  red[0][i] = tl;
  red[1][i] = (tl > 0.f) ? 1.f : 0.f;
  red[2][i] = pl;
  red[3][i] = (pl > 0.f) ? 1.f : 0.f;
  __syncthreads();
  for (int st = 128; st > 0; st >>= 1) {
    if (i < st) {
      red[0][i] += red[0][i + st];
      red[1][i] += red[1][i + st];
      red[2][i] += red[2][i + st];
      red[3][i] += red[3][i + st];
    }
    __syncthreads();
  }
  if (i == 0) {
    const float a1 = (red[1][0] > 0.f) ? red[0][0] / fmaxf(red[1][0], 1.f) : 0.f;
    const float a2 = (red[3][0] > 0.f) ? red[2][0] / fmaxf(red[3][0], 1.f) : 0.f;
    out[0] = 0.5f * (a1 + a2);
  }
}

extern "C" void kernel_launch(void* const* d_in, const int* in_sizes, int n_in,
                              void* d_out, int out_size, void* d_ws, size_t ws_size,
                              hipStream_t stream) {
  const float* net  = (const float*)d_in[0];
  const float* embs = (const float*)d_in[1];
  const float* mpts = (const float*)d_in[2];
  const float* lsc  = (const float*)d_in[3];
  // d_in[4] (pt_offset) is uniform-stride in the reference; unused.

  float* ws     = (float*)d_ws;
  float* psum   = ws + OFF_PSUM;
  float* pcnt   = ws + OFF_PCNT;
  float* avg    = ws + OFF_AVG;
  float* cnts   = ws + OFF_CNTS;
  float* logits = ws + OFF_LOG;
  float* outp   = (float*)d_out;

  k1_partial<<<dim3(BS * PB), dim3(256), 0, stream>>>(net, mpts, psum, pcnt);
  k2a_counts<<<dim3(1), dim3(256), 0, stream>>>(pcnt, cnts);
  k2b_avg<<<dim3(NT * D / 256), dim3(256), 0, stream>>>(psum, cnts, avg);
  k3_logits<<<dim3(NT), dim3(256), 0, stream>>>(embs, avg, lsc, logits);
  k4_loss<<<dim3(1), dim3(256), 0, stream>>>(logits, cnts, outp);
}

// Round 2
// 134.950 us; speedup vs baseline: 1.1039x; 1.1039x over previous
//
#include <hip/hip_runtime.h>
#include <math.h>

#define BS 8
#define NPTS 8192
#define NM 32
#define D 512
#define NT (BS*NM)           // 256 masks
#define KC 8                 // K-split factor
#define KCHUNK (NPTS/KC)     // 1024 points per block
#define KITERS (KCHUNK/32)   // 32 MFMA K-steps
#define DC 8                 // D-chunks
#define DCHUNK (D/DC)        // 64 dims per block (4 waves x 16)

typedef short short8 __attribute__((ext_vector_type(8)));
typedef float f32x4 __attribute__((ext_vector_type(4)));

// ws layout (floats):
// psum: [BS][KC][NM][D] = 1048576 (4 MB)
// cnts: [NT]
// avg:  [NT][D]
// logits: [NT][NT]
static constexpr size_t OFF_PSUM = 0;
static constexpr size_t OFF_CNTS = OFF_PSUM + (size_t)BS*KC*NM*D;
static constexpr size_t OFF_AVG  = OFF_CNTS + NT;
static constexpr size_t OFF_LOG  = OFF_AVG + (size_t)NT*D;

__device__ __forceinline__ short bf16_rne(float f) {
  uint u = __float_as_uint(f);
  return (short)(ushort)((u + 0x7fffu + ((u >> 16) & 1u)) >> 16);
}
__device__ __forceinline__ short bf16_trunc(float f) {  // exact for 0.0/1.0
  return (short)(ushort)(__float_as_uint(f) >> 16);
}

// K0: per-mask point counts (reads mask 8 MB)
__global__ __launch_bounds__(256) void k0_counts(const float* __restrict__ mpts,
                                                 float* __restrict__ cnts) {
  const int n = blockIdx.x;
  const float4* mp = (const float4*)(mpts + ((size_t)n << 13));
  float s = 0.f;
  for (int i = threadIdx.x; i < NPTS / 4; i += 256) {
    const float4 v = mp[i];
    s += v.x + v.y + v.z + v.w;
  }
  #pragma unroll
  for (int o = 32; o > 0; o >>= 1) s += __shfl_down(s, o, 64);
  __shared__ float red[4];
  if ((threadIdx.x & 63) == 0) red[threadIdx.x >> 6] = s;
  __syncthreads();
  if (threadIdx.x == 0) cnts[n] = red[0] + red[1] + red[2] + red[3];
}

// K1: masked-sum einsum via bf16 MFMA. Grid: b(8) x kc(8) x dc(8) = 512 blocks.
// Wave w owns d-tile [dc*64 + w*16, +16); computes both m-tiles (32 masks).
__global__ __launch_bounds__(256) void k1_mfma(const float* __restrict__ net,
                                               const float* __restrict__ mpts,
                                               float* __restrict__ psum) {
  const int bx = blockIdx.x;
  const int dc = bx & 7;
  const int kc = (bx >> 3) & 7;
  const int b  = bx >> 6;
  const int w    = threadIdx.x >> 6;
  const int lane = threadIdx.x & 63;
  const int lhi = lane >> 4, llo = lane & 15;
  const int d0 = dc * DCHUNK + w * 16;
  const int k0 = kc * KCHUNK;

  // B operand (net): col = d0+llo, k-rows = lhi*8 + j
  const float* np_ = net + (((size_t)b * NPTS + k0 + lhi * 8) << 9) + d0 + llo;
  // A operand (mask): row m = llo (+16 for tile1), k = lhi*8 + j (8 contiguous)
  const float* ma0 = mpts + (((size_t)(b * NM) + llo) << 13) + k0 + lhi * 8;
  const float* ma1 = ma0 + ((size_t)16 << 13);

  f32x4 acc0 = {0.f, 0.f, 0.f, 0.f};
  f32x4 acc1 = {0.f, 0.f, 0.f, 0.f};

  #pragma unroll 2
  for (int kk = 0; kk < KITERS; ++kk) {
    float bv[8];
    #pragma unroll
    for (int j = 0; j < 8; ++j) bv[j] = np_[(size_t)j << 9];
    const float4 a0lo = *(const float4*)ma0;
    const float4 a0hi = *(const float4*)(ma0 + 4);
    const float4 a1lo = *(const float4*)ma1;
    const float4 a1hi = *(const float4*)(ma1 + 4);

    short8 bf, a0f, a1f;
    #pragma unroll
    for (int j = 0; j < 8; ++j) bf[j] = bf16_rne(bv[j]);
    const float a0v[8] = {a0lo.x, a0lo.y, a0lo.z, a0lo.w, a0hi.x, a0hi.y, a0hi.z, a0hi.w};
    const float a1v[8] = {a1lo.x, a1lo.y, a1lo.z, a1lo.w, a1hi.x, a1hi.y, a1hi.z, a1hi.w};
    #pragma unroll
    for (int j = 0; j < 8; ++j) { a0f[j] = bf16_trunc(a0v[j]); a1f[j] = bf16_trunc(a1v[j]); }

    acc0 = __builtin_amdgcn_mfma_f32_16x16x32_bf16(a0f, bf, acc0, 0, 0, 0);
    acc1 = __builtin_amdgcn_mfma_f32_16x16x32_bf16(a1f, bf, acc1, 0, 0, 0);

    np_ += (size_t)32 << 9;
    ma0 += 32; ma1 += 32;
  }

  // C/D: col = lane&15 (d), row = (lane>>4)*4 + j (m) [m89-verified]
  float* op = psum + ((((size_t)b * KC + kc) * NM) << 9) + d0 + llo;
  #pragma unroll
  for (int j = 0; j < 4; ++j) {
    op[(size_t)(lhi * 4 + j) << 9]      = acc0[j];
    op[(size_t)(16 + lhi * 4 + j) << 9] = acc1[j];
  }
}

// K2: reduce K-split partials -> avg feats
__global__ __launch_bounds__(256) void k2_avg(const float* __restrict__ psum,
                                              const float* __restrict__ cnts,
                                              float* __restrict__ avg) {
  const int o = blockIdx.x * 256 + threadIdx.x;   // 0..131071
  const int n = o >> 9;
  const int d = o & (D - 1);
  const int b = n >> 5, m = n & 31;
  float s = 0.f;
  #pragma unroll
  for (int kc = 0; kc < KC; ++kc)
    s += psum[((((size_t)b * KC + kc) * NM + m) << 9) + d];
  avg[o] = s / (cnts[n] + 1e-12f);
}

// K3: logits[i][j] = exp(logit_scale) * dot(embs[i], avg[j])
__global__ __launch_bounds__(256) void k3_logits(const float* __restrict__ embs,
                                                 const float* __restrict__ avg,
                                                 const float* __restrict__ lsc,
                                                 float* __restrict__ logits) {
  const int i = blockIdx.x;
  const int j = threadIdx.x;
  __shared__ float se[D];
  for (int k = threadIdx.x; k < D; k += 256) se[k] = embs[i * D + k];
  __syncthreads();
  const float scale = expf(lsc[0]);
  const float4* __restrict__ aj = (const float4*)(avg + (size_t)j * D);
  const float4* se4 = (const float4*)se;
  float s = 0.f;
  #pragma unroll 8
  for (int k = 0; k < D / 4; ++k) {
    const float4 a = aj[k];
    const float4 e = se4[k];
    s = fmaf(e.x, a.x, s);
    s = fmaf(e.y, a.y, s);
    s = fmaf(e.z, a.z, s);
    s = fmaf(e.w, a.w, s);
  }
  logits[i * NT + j] = s * scale;
}

// K4: row/col log-softmax diagonals + nonzero-avg -> scalar
__global__ __launch_bounds__(256) void k4_loss(const float* __restrict__ logits,
                                               const float* __restrict__ cnts,
                                               float* __restrict__ out) {
  const int i = threadIdx.x;

  float mx = -1e30f;
  for (int j = 0; j < NT; ++j) mx = fmaxf(mx, logits[i * NT + j]);
  float s = 0.f;
  for (int j = 0; j < NT; ++j) s += expf(logits[i * NT + j] - mx);
  const float rowlse = mx + logf(s);

  float mc = -1e30f;
  for (int k = 0; k < NT; ++k) mc = fmaxf(mc, logits[k * NT + i]);
  float sc = 0.f;
  for (int k = 0; k < NT; ++k) sc += expf(logits[k * NT + i] - mc);
  const float collse = mc + logf(sc);

  const float diag = logits[i * NT + i];
  const bool valid = cnts[i] > 0.f;
  const float tl = valid ? (rowlse - diag) : 0.f;
  const float pl = valid ? (collse - diag) : 0.f;

  __shared__ float red[4][256];
  red[0][i] = tl;
  red[1][i] = (tl > 0.f) ? 1.f : 0.f;
  red[2][i] = pl;
  red[3][i] = (pl > 0.f) ? 1.f : 0.f;
  __syncthreads();
  for (int st = 128; st > 0; st >>= 1) {
    if (i < st) {
      red[0][i] += red[0][i + st];
      red[1][i] += red[1][i + st];
      red[2][i] += red[2][i + st];
      red[3][i] += red[3][i + st];
    }
    __syncthreads();
  }
  if (i == 0) {
    const float a1 = (red[1][0] > 0.f) ? red[0][0] / fmaxf(red[1][0], 1.f) : 0.f;
    const float a2 = (red[3][0] > 0.f) ? red[2][0] / fmaxf(red[3][0], 1.f) : 0.f;
    out[0] = 0.5f * (a1 + a2);
  }
}

extern "C" void kernel_launch(void* const* d_in, const int* in_sizes, int n_in,
                              void* d_out, int out_size, void* d_ws, size_t ws_size,
                              hipStream_t stream) {
  const float* net  = (const float*)d_in[0];
  const float* embs = (const float*)d_in[1];
  const float* mpts = (const float*)d_in[2];
  const float* lsc  = (const float*)d_in[3];

  float* ws     = (float*)d_ws;
  float* psum   = ws + OFF_PSUM;
  float* cnts   = ws + OFF_CNTS;
  float* avg    = ws + OFF_AVG;
  float* logits = ws + OFF_LOG;
  float* outp   = (float*)d_out;

  k0_counts<<<dim3(NT), dim3(256), 0, stream>>>(mpts, cnts);
  k1_mfma<<<dim3(BS * KC * DC), dim3(256), 0, stream>>>(net, mpts, psum);
  k2_avg<<<dim3(NT * D / 256), dim3(256), 0, stream>>>(psum, cnts, avg);
  k3_logits<<<dim3(NT), dim3(256), 0, stream>>>(embs, avg, lsc, logits);
  k4_loss<<<dim3(1), dim3(256), 0, stream>>>(logits, cnts, outp);
}

// Round 3
// 118.619 us; speedup vs baseline: 1.2559x; 1.1377x over previous
//
#include <hip/hip_runtime.h>
#include <math.h>

#define BS 8
#define NPTS 8192
#define NM 32
#define D 512
#define NT (BS*NM)           // 256 masks
#define KC 16                // K-split factor
#define KCHUNK (NPTS/KC)     // 512 points per block
#define KITERS (KCHUNK/32)   // 16 MFMA K-steps
#define DC 8                 // D-chunks
#define DCHUNK (D/DC)        // 64 dims per block (4 waves x 16)

typedef short short8 __attribute__((ext_vector_type(8)));
typedef float f32x4 __attribute__((ext_vector_type(4)));

// ws layout (floats):
static constexpr size_t OFF_PSUM = 0;                               // [BS][KC][NM][D] = 4M floats (16 MB)
static constexpr size_t OFF_PCNT = OFF_PSUM + (size_t)BS*KC*NM*D;   // [BS*KC][NM]
static constexpr size_t OFF_CNTS = OFF_PCNT + (size_t)BS*KC*NM;     // [NT]
static constexpr size_t OFF_AVG  = OFF_CNTS + NT;                   // [NT][D]
static constexpr size_t OFF_RLSE = OFF_AVG + (size_t)NT*D;          // [NT]
static constexpr size_t OFF_LOG  = OFF_RLSE + NT;                   // [NT][NT]

__device__ __forceinline__ short bf16_rne(float f) {
  uint u = __float_as_uint(f);
  return (short)(ushort)((u + 0x7fffu + ((u >> 16) & 1u)) >> 16);
}
__device__ __forceinline__ short bf16_trunc(float f) {  // exact for 0.0/1.0
  return (short)(ushort)(__float_as_uint(f) >> 16);
}

// K1: masked-sum einsum via bf16 MFMA + fused partial counts.
// Grid: b(8) x kc(16) x dc(8) = 1024 blocks (4/CU -> 16 waves/CU).
__global__ __launch_bounds__(256) void k1_mfma(const float* __restrict__ net,
                                               const float* __restrict__ mpts,
                                               float* __restrict__ psum,
                                               float* __restrict__ pcnt) {
  const int bx = blockIdx.x;
  const int dc = bx & 7;
  const int kc = (bx >> 3) & 15;
  const int b  = bx >> 7;
  const int w    = threadIdx.x >> 6;
  const int lane = threadIdx.x & 63;
  const int lhi = lane >> 4, llo = lane & 15;
  const int d0 = dc * DCHUNK + w * 16;
  const int k0 = kc * KCHUNK;
  const bool docnt = (dc == 0) && (w == 0);

  // B operand (net): col = d0+llo, k-rows = lhi*8 + j
  const float* np_ = net + (((size_t)b * NPTS + k0 + lhi * 8) << 9) + d0 + llo;
  // A operand (mask): row m = llo (+16 for tile1), k = lhi*8 + j
  const float* ma0 = mpts + (((size_t)(b * NM) + llo) << 13) + k0 + lhi * 8;
  const float* ma1 = ma0 + ((size_t)16 << 13);

  f32x4 acc0 = {0.f, 0.f, 0.f, 0.f};
  f32x4 acc1 = {0.f, 0.f, 0.f, 0.f};
  float c0 = 0.f, c1 = 0.f;

  #pragma unroll 4
  for (int kk = 0; kk < KITERS; ++kk) {
    float bv[8];
    #pragma unroll
    for (int j = 0; j < 8; ++j) bv[j] = np_[(size_t)j << 9];
    const float4 a0lo = *(const float4*)ma0;
    const float4 a0hi = *(const float4*)(ma0 + 4);
    const float4 a1lo = *(const float4*)ma1;
    const float4 a1hi = *(const float4*)(ma1 + 4);

    short8 bf, a0f, a1f;
    #pragma unroll
    for (int j = 0; j < 8; ++j) bf[j] = bf16_rne(bv[j]);
    const float a0v[8] = {a0lo.x, a0lo.y, a0lo.z, a0lo.w, a0hi.x, a0hi.y, a0hi.z, a0hi.w};
    const float a1v[8] = {a1lo.x, a1lo.y, a1lo.z, a1lo.w, a1hi.x, a1hi.y, a1hi.z, a1hi.w};
    #pragma unroll
    for (int j = 0; j < 8; ++j) { a0f[j] = bf16_trunc(a0v[j]); a1f[j] = bf16_trunc(a1v[j]); }

    if (docnt) {
      #pragma unroll
      for (int j = 0; j < 8; ++j) { c0 += a0v[j]; c1 += a1v[j]; }
    }

    acc0 = __builtin_amdgcn_mfma_f32_16x16x32_bf16(a0f, bf, acc0, 0, 0, 0);
    acc1 = __builtin_amdgcn_mfma_f32_16x16x32_bf16(a1f, bf, acc1, 0, 0, 0);

    np_ += (size_t)32 << 9;
    ma0 += 32; ma1 += 32;
  }

  // C/D: col = lane&15 (d), row = (lane>>4)*4 + j (m) [m89-verified]
  float* op = psum + ((((size_t)b * KC + kc) * NM) << 9) + d0 + llo;
  #pragma unroll
  for (int j = 0; j < 4; ++j) {
    op[(size_t)(lhi * 4 + j) << 9]      = acc0[j];
    op[(size_t)(16 + lhi * 4 + j) << 9] = acc1[j];
  }

  if (docnt) {
    c0 += __shfl_xor(c0, 16, 64); c0 += __shfl_xor(c0, 32, 64);
    c1 += __shfl_xor(c1, 16, 64); c1 += __shfl_xor(c1, 32, 64);
    if (lhi == 0) {
      pcnt[(b * KC + kc) * NM + llo]      = c0;
      pcnt[(b * KC + kc) * NM + 16 + llo] = c1;
    }
  }
}

// K2: per-mask reduce of K-partials + counts -> avg, cnts. Grid: 256 blocks.
__global__ __launch_bounds__(256) void k2_avg(const float* __restrict__ psum,
                                              const float* __restrict__ pcnt,
                                              float* __restrict__ cnts,
                                              float* __restrict__ avg) {
  const int n = blockIdx.x;
  const int b = n >> 5, m = n & 31;
  const int t = threadIdx.x;

  float cnt = 0.f;
  #pragma unroll
  for (int kc = 0; kc < KC; ++kc) cnt += pcnt[(b * KC + kc) * NM + m];
  if (t == 0) cnts[n] = cnt;
  const float inv = 1.f / (cnt + 1e-12f);

  float2 s = {0.f, 0.f};
  #pragma unroll
  for (int kc = 0; kc < KC; ++kc) {
    const float2 v = *(const float2*)(psum + ((((size_t)b * KC + kc) * NM + m) << 9) + 2 * t);
    s.x += v.x; s.y += v.y;
  }
  *(float2*)(avg + (size_t)n * D + 2 * t) = make_float2(s.x * inv, s.y * inv);
}

// K3: logits row i + fused row-LSE.
__global__ __launch_bounds__(256) void k3_logits(const float* __restrict__ embs,
                                                 const float* __restrict__ avg,
                                                 const float* __restrict__ lsc,
                                                 float* __restrict__ logits,
                                                 float* __restrict__ rowlse) {
  const int i = blockIdx.x;
  const int j = threadIdx.x;
  __shared__ float se[D];
  __shared__ float red[256];
  for (int k = j; k < D; k += 256) se[k] = embs[i * D + k];
  __syncthreads();
  const float scale = expf(lsc[0]);
  const float4* __restrict__ aj = (const float4*)(avg + (size_t)j * D);
  const float4* se4 = (const float4*)se;
  float s = 0.f;
  #pragma unroll 8
  for (int k = 0; k < D / 4; ++k) {
    const float4 a = aj[k];
    const float4 e = se4[k];
    s = fmaf(e.x, a.x, s);
    s = fmaf(e.y, a.y, s);
    s = fmaf(e.z, a.z, s);
    s = fmaf(e.w, a.w, s);
  }
  const float lg = s * scale;
  logits[i * NT + j] = lg;

  red[j] = lg;
  __syncthreads();
  for (int st = 128; st > 0; st >>= 1) {
    if (j < st) red[j] = fmaxf(red[j], red[j + st]);
    __syncthreads();
  }
  const float mx = red[0];
  __syncthreads();
  red[j] = expf(lg - mx);
  __syncthreads();
  for (int st = 128; st > 0; st >>= 1) {
    if (j < st) red[j] += red[j + st];
    __syncthreads();
  }
  if (j == 0) rowlse[i] = mx + logf(red[0]);
}

// K4: coalesced col-LSE + final nonzero-avg -> scalar.
__global__ __launch_bounds__(256) void k4_loss(const float* __restrict__ logits,
                                               const float* __restrict__ rowlse,
                                               const float* __restrict__ cnts,
                                               float* __restrict__ out) {
  const int i = threadIdx.x;

  float mc = -1e30f;
  #pragma unroll 4
  for (int k = 0; k < NT; ++k) mc = fmaxf(mc, logits[k * NT + i]);
  float sc = 0.f;
  #pragma unroll 4
  for (int k = 0; k < NT; ++k) sc += expf(logits[k * NT + i] - mc);
  const float collse = mc + logf(sc);

  const float diag = logits[i * NT + i];
  const bool valid = cnts[i] > 0.f;
  const float tl = valid ? (rowlse[i] - diag) : 0.f;
  const float pl = valid ? (collse - diag) : 0.f;

  __shared__ float red[4][256];
  red[0][i] = tl;
  red[1][i] = (tl > 0.f) ? 1.f : 0.f;
  red[2][i] = pl;
  red[3][i] = (pl > 0.f) ? 1.f : 0.f;
  __syncthreads();
  for (int st = 128; st > 0; st >>= 1) {
    if (i < st) {
      red[0][i] += red[0][i + st];
      red[1][i] += red[1][i + st];
      red[2][i] += red[2][i + st];
      red[3][i] += red[3][i + st];
    }
    __syncthreads();
  }
  if (i == 0) {
    const float a1 = (red[1][0] > 0.f) ? red[0][0] / fmaxf(red[1][0], 1.f) : 0.f;
    const float a2 = (red[3][0] > 0.f) ? red[2][0] / fmaxf(red[3][0], 1.f) : 0.f;
    out[0] = 0.5f * (a1 + a2);
  }
}

extern "C" void kernel_launch(void* const* d_in, const int* in_sizes, int n_in,
                              void* d_out, int out_size, void* d_ws, size_t ws_size,
                              hipStream_t stream) {
  const float* net  = (const float*)d_in[0];
  const float* embs = (const float*)d_in[1];
  const float* mpts = (const float*)d_in[2];
  const float* lsc  = (const float*)d_in[3];

  float* ws     = (float*)d_ws;
  float* psum   = ws + OFF_PSUM;
  float* pcnt   = ws + OFF_PCNT;
  float* cnts   = ws + OFF_CNTS;
  float* avg    = ws + OFF_AVG;
  float* rowlse = ws + OFF_RLSE;
  float* logits = ws + OFF_LOG;
  float* outp   = (float*)d_out;

  k1_mfma<<<dim3(BS * KC * DC), dim3(256), 0, stream>>>(net, mpts, psum, pcnt);
  k2_avg<<<dim3(NT), dim3(256), 0, stream>>>(psum, pcnt, cnts, avg);
  k3_logits<<<dim3(NT), dim3(256), 0, stream>>>(embs, avg, lsc, logits, rowlse);
  k4_loss<<<dim3(1), dim3(256), 0, stream>>>(logits, rowlse, cnts, outp);
}

// Round 4
// 68.061 us; speedup vs baseline: 2.1887x; 1.7428x over previous
//
#include <hip/hip_runtime.h>
#include <math.h>

#define BS 8
#define NPTS 8192
#define NM 32
#define D 512
#define NT (BS*NM)            // 256 masks
#define KC 32                 // K-split factor
#define KCHUNK (NPTS/KC)      // 256 points per block
#define TILES (KCHUNK/32)     // 8 k-tiles of 32
#define DC 8                  // D-chunks
#define DCHUNK (D/DC)         // 64 dims per block (4 waves x 16)

typedef short short8 __attribute__((ext_vector_type(8)));
typedef float f32x4 __attribute__((ext_vector_type(4)));

// ws layout (floats):
static constexpr size_t OFF_PSUM = 0;                               // [BS*KC][NM][D] = 4M (16MB)
static constexpr size_t OFF_PCNT = OFF_PSUM + (size_t)BS*KC*NM*D;   // [BS*KC][NM]
static constexpr size_t OFF_CNTS = OFF_PCNT + (size_t)BS*KC*NM;     // [NT]
static constexpr size_t OFF_AVG  = OFF_CNTS + NT;                   // [NT][D]
static constexpr size_t OFF_RLSE = OFF_AVG + (size_t)NT*D;          // [NT]
static constexpr size_t OFF_CLSE = OFF_RLSE + NT;                   // [NT]
static constexpr size_t OFF_LOG  = OFF_CLSE + NT;                   // [NT][NT]

__device__ __forceinline__ short bf16_rne(float f) {
  uint u = __float_as_uint(f);
  return (short)(ushort)((u + 0x7fffu + ((u >> 16) & 1u)) >> 16);
}
__device__ __forceinline__ short bf16_trunc(float f) {  // exact for 0.0/1.0
  return (short)(ushort)(__float_as_uint(f) >> 16);
}

#define GLOAD_LDS16(g, l) __builtin_amdgcn_global_load_lds( \
    (const __attribute__((address_space(1))) void*)(g),     \
    (__attribute__((address_space(3))) void*)(l), 16, 0, 0)

// K1: masked-sum einsum via bf16 MFMA with global_load_lds-staged net tiles.
// Grid: b(8) x kc(32) x dc(8) = 2048 blocks -> 8 blocks/CU, 32 waves/CU.
__global__ __launch_bounds__(256, 8) void k1_mfma(const float* __restrict__ net,
                                                  const float* __restrict__ mpts,
                                                  float* __restrict__ psum,
                                                  float* __restrict__ pcnt) {
  __shared__ float tile[2][32 * DCHUNK];   // [k=32][d=64] f32, 8KB per buffer
  const int bx = blockIdx.x;
  const int dc = bx & 7;
  const int kc = (bx >> 3) & 31;
  const int b  = bx >> 8;
  const int w    = threadIdx.x >> 6;
  const int lane = threadIdx.x & 63;
  const int lhi = lane >> 4, llo = lane & 15;
  const int k0 = kc * KCHUNK;
  const bool docnt = (dc == 0) && (w == 0);

  // stage k-tile t into tile[buf]: wave w issues segments 2w, 2w+1 (1KB each)
  auto stage = [&](int buf, int t) {
    const int kt = k0 + t * 32;
    #pragma unroll
    for (int si = 0; si < 2; ++si) {
      const int s = w * 2 + si;
      const float* src = net
        + (((size_t)(b * NPTS + kt + s * 4 + (lane >> 4))) << 9)
        + dc * DCHUNK + ((lane & 15) << 2);
      GLOAD_LDS16(src, &tile[buf][s * 256]);
    }
  };

  // A operand (mask): row m = llo (+16 for tile1), k = lhi*8 + j within 32-k tile
  const float* ma0 = mpts + (((size_t)(b * NM) + llo) << 13) + k0 + lhi * 8;
  const float* ma1 = ma0 + ((size_t)16 << 13);

  f32x4 acc0 = {0.f, 0.f, 0.f, 0.f};
  f32x4 acc1 = {0.f, 0.f, 0.f, 0.f};
  float c0 = 0.f, c1 = 0.f;

  stage(0, 0);
  __syncthreads();

  for (int t = 0; t < TILES; ++t) {
    const int cur = t & 1;
    // A direct loads FIRST (so the compiler's counted vmcnt wait for them
    // leaves the just-issued next-tile stage in flight)
    const float4 a0lo = *(const float4*)(ma0);
    const float4 a0hi = *(const float4*)(ma0 + 4);
    const float4 a1lo = *(const float4*)(ma1);
    const float4 a1hi = *(const float4*)(ma1 + 4);
    if (t + 1 < TILES) stage(cur ^ 1, t + 1);

    // B frag from LDS: d = w*16+llo, k = lhi*8+j
    float bv[8];
    const int bbase = lhi * 8 * DCHUNK + w * 16 + llo;
    #pragma unroll
    for (int j = 0; j < 8; ++j) bv[j] = tile[cur][bbase + j * DCHUNK];

    short8 bf, a0f, a1f;
    #pragma unroll
    for (int j = 0; j < 8; ++j) bf[j] = bf16_rne(bv[j]);
    const float a0v[8] = {a0lo.x, a0lo.y, a0lo.z, a0lo.w, a0hi.x, a0hi.y, a0hi.z, a0hi.w};
    const float a1v[8] = {a1lo.x, a1lo.y, a1lo.z, a1lo.w, a1hi.x, a1hi.y, a1hi.z, a1hi.w};
    #pragma unroll
    for (int j = 0; j < 8; ++j) { a0f[j] = bf16_trunc(a0v[j]); a1f[j] = bf16_trunc(a1v[j]); }

    if (docnt) {
      #pragma unroll
      for (int j = 0; j < 8; ++j) { c0 += a0v[j]; c1 += a1v[j]; }
    }

    acc0 = __builtin_amdgcn_mfma_f32_16x16x32_bf16(a0f, bf, acc0, 0, 0, 0);
    acc1 = __builtin_amdgcn_mfma_f32_16x16x32_bf16(a1f, bf, acc1, 0, 0, 0);

    __syncthreads();   // stage(t+1) drained; all waves done reading tile[cur]
    ma0 += 32; ma1 += 32;
  }

  // C/D: col = lane&15 (d), row = (lane>>4)*4 + j (m) [m89-verified]
  const int d0 = dc * DCHUNK + w * 16;
  float* op = psum + ((((size_t)b * KC + kc) * NM) << 9) + d0 + llo;
  #pragma unroll
  for (int j = 0; j < 4; ++j) {
    op[(size_t)(lhi * 4 + j) << 9]      = acc0[j];
    op[(size_t)(16 + lhi * 4 + j) << 9] = acc1[j];
  }

  if (docnt) {
    c0 += __shfl_xor(c0, 16, 64); c0 += __shfl_xor(c0, 32, 64);
    c1 += __shfl_xor(c1, 16, 64); c1 += __shfl_xor(c1, 32, 64);
    if (lhi == 0) {
      pcnt[(b * KC + kc) * NM + llo]      = c0;
      pcnt[(b * KC + kc) * NM + 16 + llo] = c1;
    }
  }
}

// K2: per-mask reduce of K-partials + counts -> avg, cnts. Grid: 256 blocks.
__global__ __launch_bounds__(256) void k2_avg(const float* __restrict__ psum,
                                              const float* __restrict__ pcnt,
                                              float* __restrict__ cnts,
                                              float* __restrict__ avg) {
  const int n = blockIdx.x;
  const int b = n >> 5, m = n & 31;
  const int t = threadIdx.x;

  float cnt = 0.f;
  #pragma unroll
  for (int kc = 0; kc < KC; ++kc) cnt += pcnt[(b * KC + kc) * NM + m];
  if (t == 0) cnts[n] = cnt;
  const float inv = 1.f / (cnt + 1e-12f);

  float2 s = {0.f, 0.f};
  #pragma unroll 8
  for (int kc = 0; kc < KC; ++kc) {
    const float2 v = *(const float2*)(psum + ((((size_t)b * KC + kc) * NM + m) << 9) + 2 * t);
    s.x += v.x; s.y += v.y;
  }
  *(float2*)(avg + (size_t)n * D + 2 * t) = make_float2(s.x * inv, s.y * inv);
}

// K3: logits = exp(lsc) * embs @ avg^T via bf16 MFMA.
// Grid: 64 blocks x 4 waves = 256 wave-tiles of 16x16.
__global__ __launch_bounds__(256) void k3_logits(const float* __restrict__ embs,
                                                 const float* __restrict__ avg,
                                                 const float* __restrict__ lsc,
                                                 float* __restrict__ logits) {
  const int w = threadIdx.x >> 6, lane = threadIdx.x & 63;
  const int wt = blockIdx.x * 4 + w;        // 0..255
  const int ti = wt >> 4, tj = wt & 15;
  const int lhi = lane >> 4, llo = lane & 15;
  const float scale = expf(lsc[0]);

  const float* ea = embs + (((size_t)(ti * 16 + llo)) << 9) + lhi * 8;
  const float* av = avg  + (((size_t)(tj * 16 + llo)) << 9) + lhi * 8;
  f32x4 acc = {0.f, 0.f, 0.f, 0.f};
  #pragma unroll 4
  for (int kk = 0; kk < D / 32; ++kk) {
    const float4 e0 = *(const float4*)(ea);
    const float4 e1 = *(const float4*)(ea + 4);
    const float4 v0 = *(const float4*)(av);
    const float4 v1 = *(const float4*)(av + 4);
    const float ev[8] = {e0.x, e0.y, e0.z, e0.w, e1.x, e1.y, e1.z, e1.w};
    const float vv[8] = {v0.x, v0.y, v0.z, v0.w, v1.x, v1.y, v1.z, v1.w};
    short8 ef, vf;
    #pragma unroll
    for (int j = 0; j < 8; ++j) { ef[j] = bf16_rne(ev[j]); vf[j] = bf16_rne(vv[j]); }
    acc = __builtin_amdgcn_mfma_f32_16x16x32_bf16(ef, vf, acc, 0, 0, 0);
    ea += 32; av += 32;
  }
  // C/D: col=llo -> n (avg row), row=lhi*4+r -> m (embs row)
  float* lp = logits + (size_t)(ti * 16) * NT + tj * 16 + llo;
  #pragma unroll
  for (int r = 0; r < 4; ++r)
    lp[(size_t)(lhi * 4 + r) * NT] = acc[r] * scale;
}

// K4: LSEs. Blocks 0..15: collse for 16 cols each; 16..31: rowlse for 16 rows.
__global__ __launch_bounds__(256) void k4_lse(const float* __restrict__ logits,
                                              float* __restrict__ rowlse,
                                              float* __restrict__ clse) {
  const int g = blockIdx.x;
  const int r = threadIdx.x >> 4;
  const int c = threadIdx.x & 15;
  __shared__ float red[16][17];
  if (g < 16) {
    const int col = g * 16 + c;
    float mx = -1e30f;
    #pragma unroll 4
    for (int kk = 0; kk < 16; ++kk) mx = fmaxf(mx, logits[(size_t)(kk * 16 + r) * NT + col]);
    red[r][c] = mx; __syncthreads();
    for (int st = 8; st; st >>= 1) { if (r < st) red[r][c] = fmaxf(red[r][c], red[r + st][c]); __syncthreads(); }
    mx = red[0][c]; __syncthreads();
    float s = 0.f;
    #pragma unroll 4
    for (int kk = 0; kk < 16; ++kk) s += expf(logits[(size_t)(kk * 16 + r) * NT + col] - mx);
    red[r][c] = s; __syncthreads();
    for (int st = 8; st; st >>= 1) { if (r < st) red[r][c] += red[r + st][c]; __syncthreads(); }
    if (r == 0) clse[col] = mx + logf(red[0][c]);
  } else {
    const int row = (g - 16) * 16 + r;
    float mx = -1e30f;
    #pragma unroll 4
    for (int kk = 0; kk < 16; ++kk) mx = fmaxf(mx, logits[(size_t)row * NT + kk * 16 + c]);
    #pragma unroll
    for (int o = 8; o; o >>= 1) mx = fmaxf(mx, __shfl_xor(mx, o, 64));
    float s = 0.f;
    #pragma unroll 4
    for (int kk = 0; kk < 16; ++kk) s += expf(logits[(size_t)row * NT + kk * 16 + c] - mx);
    #pragma unroll
    for (int o = 8; o; o >>= 1) s += __shfl_xor(s, o, 64);
    if (c == 0) rowlse[row] = mx + logf(s);
  }
}

// K5: final nonzero-avg -> scalar.
__global__ __launch_bounds__(256) void k5_loss(const float* __restrict__ logits,
                                               const float* __restrict__ rowlse,
                                               const float* __restrict__ clse,
                                               const float* __restrict__ cnts,
                                               float* __restrict__ out) {
  const int i = threadIdx.x;
  const float diag = logits[(size_t)i * NT + i];
  const bool valid = cnts[i] > 0.f;
  const float tl = valid ? (rowlse[i] - diag) : 0.f;
  const float pl = valid ? (clse[i] - diag) : 0.f;

  __shared__ float red[4][256];
  red[0][i] = tl;
  red[1][i] = (tl > 0.f) ? 1.f : 0.f;
  red[2][i] = pl;
  red[3][i] = (pl > 0.f) ? 1.f : 0.f;
  __syncthreads();
  for (int st = 128; st > 0; st >>= 1) {
    if (i < st) {
      red[0][i] += red[0][i + st];
      red[1][i] += red[1][i + st];
      red[2][i] += red[2][i + st];
      red[3][i] += red[3][i + st];
    }
    __syncthreads();
  }
  if (i == 0) {
    const float a1 = (red[1][0] > 0.f) ? red[0][0] / fmaxf(red[1][0], 1.f) : 0.f;
    const float a2 = (red[3][0] > 0.f) ? red[2][0] / fmaxf(red[3][0], 1.f) : 0.f;
    out[0] = 0.5f * (a1 + a2);
  }
}

extern "C" void kernel_launch(void* const* d_in, const int* in_sizes, int n_in,
                              void* d_out, int out_size, void* d_ws, size_t ws_size,
                              hipStream_t stream) {
  const float* net  = (const float*)d_in[0];
  const float* embs = (const float*)d_in[1];
  const float* mpts = (const float*)d_in[2];
  const float* lsc  = (const float*)d_in[3];

  float* ws     = (float*)d_ws;
  float* psum   = ws + OFF_PSUM;
  float* pcnt   = ws + OFF_PCNT;
  float* cnts   = ws + OFF_CNTS;
  float* avg    = ws + OFF_AVG;
  float* rowlse = ws + OFF_RLSE;
  float* clse   = ws + OFF_CLSE;
  float* logits = ws + OFF_LOG;
  float* outp   = (float*)d_out;

  k1_mfma<<<dim3(BS * KC * DC), dim3(256), 0, stream>>>(net, mpts, psum, pcnt);
  k2_avg<<<dim3(NT), dim3(256), 0, stream>>>(psum, pcnt, cnts, avg);
  k3_logits<<<dim3(64), dim3(256), 0, stream>>>(embs, avg, lsc, logits);
  k4_lse<<<dim3(32), dim3(256), 0, stream>>>(logits, rowlse, clse);
  k5_loss<<<dim3(1), dim3(256), 0, stream>>>(logits, rowlse, clse, cnts, outp);
}

// Round 5
// 67.930 us; speedup vs baseline: 2.1929x; 1.0019x over previous
//
#include <hip/hip_runtime.h>
#include <hip/hip_bf16.h>
#include <math.h>

#define BS 8
#define NPTS 8192
#define NM 32
#define D 512
#define NT (BS*NM)            // 256 masks
#define KC 32                 // K-split factor
#define KCHUNK (NPTS/KC)      // 256 points per block
#define TILES (KCHUNK/32)     // 8 k-tiles of 32
#define DC 8                  // D-chunks
#define DCHUNK (D/DC)         // 64 dims per block (4 waves x 16)

#define LOG2E 1.44269504088896f
#define LN2   0.69314718055995f

typedef short short8 __attribute__((ext_vector_type(8)));
typedef float f32x4 __attribute__((ext_vector_type(4)));

// ws layout (floats):
static constexpr size_t OFF_SUMF = 0;                      // [NT][D] = 131072 (atomic acc)
static constexpr size_t OFF_CNTS = OFF_SUMF + (size_t)NT*D;// [NT]    = 256   (atomic acc)
static constexpr size_t OFF_LOG  = OFF_CNTS + NT;          // [NT][NT]
static constexpr size_t OFF_RLSE = OFF_LOG + (size_t)NT*NT;// [NT]
static constexpr size_t OFF_CLSE = OFF_RLSE + NT;          // [NT]
#define NZERO ((int)(OFF_LOG))   // floats to zero before k1 = 131328

__device__ __forceinline__ short bf16_rne(float f) {
  return __builtin_bit_cast(short, __float2bfloat16(f));
}
__device__ __forceinline__ short bf16_trunc(float f) {  // exact for 0.0/1.0
  return (short)(ushort)(__float_as_uint(f) >> 16);
}

#define GLOAD_LDS16(g, l) __builtin_amdgcn_global_load_lds( \
    (const __attribute__((address_space(1))) void*)(g),     \
    (__attribute__((address_space(3))) void*)(l), 16, 0, 0)

// KZ: zero the atomic accumulators (sumf + cnts).
__global__ __launch_bounds__(256) void kz_zero(float* __restrict__ ws) {
  const int i = blockIdx.x * 256 + threadIdx.x;
  if (i < NZERO / 4) ((float4*)ws)[i] = make_float4(0.f, 0.f, 0.f, 0.f);
}

// K1: masked-sum einsum via bf16 MFMA, global_load_lds-staged net tiles
// (XOR-swizzled granules: LDS granule g' holds global granule g = g'^((k>>3)<<2)),
// atomicAdd epilogue into sumf. Grid: b(8) x kc(32) x dc(8) = 2048 blocks.
__global__ __launch_bounds__(256, 8) void k1_mfma(const float* __restrict__ net,
                                                  const float* __restrict__ mpts,
                                                  float* __restrict__ sumf,
                                                  float* __restrict__ cnts) {
  __shared__ float tile[2][32 * DCHUNK];   // [k=32][16 granules of 4 f32], 8KB/buf
  const int bx = blockIdx.x;
  const int dc = bx & 7;
  const int kc = (bx >> 3) & 31;
  const int b  = bx >> 8;
  const int w    = threadIdx.x >> 6;
  const int lane = threadIdx.x & 63;
  const int lhi = lane >> 4, llo = lane & 15;
  const int k0 = kc * KCHUNK;
  const bool docnt = (dc == 0) && (w == 0);

  // stage k-tile t into tile[buf]; wave w issues segments s=2w,2w+1 (1KB each).
  // dest lane-linear; global src granule pre-swizzled: g = (lane&15) ^ (((s>>1)&3)<<2)
  auto stage = [&](int buf, int t) {
    const int kt = k0 + t * 32;
    #pragma unroll
    for (int si = 0; si < 2; ++si) {
      const int s = w * 2 + si;
      const int gsrc = (lane & 15) ^ (((s >> 1) & 3) << 2);
      const float* src = net
        + (((size_t)(b * NPTS + kt + s * 4 + (lane >> 4))) << 9)
        + dc * DCHUNK + (gsrc << 2);
      GLOAD_LDS16(src, &tile[buf][s * 256]);
    }
  };

  // A operand (mask): row m = llo (+16 for tile1), k = lhi*8 + j
  const float* ma0 = mpts + (((size_t)(b * NM) + llo) << 13) + k0 + lhi * 8;
  const float* ma1 = ma0 + ((size_t)16 << 13);

  f32x4 acc0 = {0.f, 0.f, 0.f, 0.f};
  f32x4 acc1 = {0.f, 0.f, 0.f, 0.f};
  float c0 = 0.f, c1 = 0.f;

  // swizzled per-lane LDS read base: k-row lhi*8, granule (w*4+(llo>>2))^(lhi<<2), sub llo&3
  const int rbase = (lhi * 8) * 64 + ((((w * 4) + (llo >> 2)) ^ (lhi << 2)) << 2) + (llo & 3);

  stage(0, 0);
  __syncthreads();

  for (int t = 0; t < TILES; ++t) {
    const int cur = t & 1;
    const float4 a0lo = *(const float4*)(ma0);
    const float4 a0hi = *(const float4*)(ma0 + 4);
    const float4 a1lo = *(const float4*)(ma1);
    const float4 a1hi = *(const float4*)(ma1 + 4);
    if (t + 1 < TILES) stage(cur ^ 1, t + 1);

    float bv[8];
    #pragma unroll
    for (int j = 0; j < 8; ++j) bv[j] = tile[cur][rbase + j * 64];

    short8 bf, a0f, a1f;
    #pragma unroll
    for (int j = 0; j < 8; ++j) bf[j] = bf16_rne(bv[j]);
    const float a0v[8] = {a0lo.x, a0lo.y, a0lo.z, a0lo.w, a0hi.x, a0hi.y, a0hi.z, a0hi.w};
    const float a1v[8] = {a1lo.x, a1lo.y, a1lo.z, a1lo.w, a1hi.x, a1hi.y, a1hi.z, a1hi.w};
    #pragma unroll
    for (int j = 0; j < 8; ++j) { a0f[j] = bf16_trunc(a0v[j]); a1f[j] = bf16_trunc(a1v[j]); }

    if (docnt) {
      #pragma unroll
      for (int j = 0; j < 8; ++j) { c0 += a0v[j]; c1 += a1v[j]; }
    }

    acc0 = __builtin_amdgcn_mfma_f32_16x16x32_bf16(a0f, bf, acc0, 0, 0, 0);
    acc1 = __builtin_amdgcn_mfma_f32_16x16x32_bf16(a1f, bf, acc1, 0, 0, 0);

    __syncthreads();
    ma0 += 32; ma1 += 32;
  }

  // C/D: col = llo (d), row = lhi*4 + j (m) [m89-verified]; accumulate via atomics
  const int d0 = dc * DCHUNK + w * 16;
  float* sp = sumf + (((size_t)(b * NM)) << 9) + d0 + llo;
  #pragma unroll
  for (int j = 0; j < 4; ++j) {
    atomicAdd(sp + ((size_t)(lhi * 4 + j) << 9),      acc0[j]);
    atomicAdd(sp + ((size_t)(16 + lhi * 4 + j) << 9), acc1[j]);
  }

  if (docnt) {
    c0 += __shfl_xor(c0, 16, 64); c0 += __shfl_xor(c0, 32, 64);
    c1 += __shfl_xor(c1, 16, 64); c1 += __shfl_xor(c1, 32, 64);
    if (lhi == 0) {   // counts are integer-valued: atomic order-exact
      atomicAdd(&cnts[b * NM + llo],      c0);
      atomicAdd(&cnts[b * NM + 16 + llo], c1);
    }
  }
}

// K2: logits = exp(lsc) * (embs @ sumf^T) * inv_cnt[col], bf16 MFMA.
// Grid: 64 blocks x 4 waves = 256 wave-tiles of 16x16.
__global__ __launch_bounds__(256) void k2_logits(const float* __restrict__ embs,
                                                 const float* __restrict__ sumf,
                                                 const float* __restrict__ cnts,
                                                 const float* __restrict__ lsc,
                                                 float* __restrict__ logits) {
  const int w = threadIdx.x >> 6, lane = threadIdx.x & 63;
  const int wt = blockIdx.x * 4 + w;        // 0..255
  const int ti = wt >> 4, tj = wt & 15;
  const int lhi = lane >> 4, llo = lane & 15;
  const float scale = expf(lsc[0]);

  const float* ea = embs + (((size_t)(ti * 16 + llo)) << 9) + lhi * 8;
  const float* sv = sumf + (((size_t)(tj * 16 + llo)) << 9) + lhi * 8;
  f32x4 acc = {0.f, 0.f, 0.f, 0.f};
  #pragma unroll 4
  for (int kk = 0; kk < D / 32; ++kk) {
    const float4 e0 = *(const float4*)(ea);
    const float4 e1 = *(const float4*)(ea + 4);
    const float4 v0 = *(const float4*)(sv);
    const float4 v1 = *(const float4*)(sv + 4);
    const float ev[8] = {e0.x, e0.y, e0.z, e0.w, e1.x, e1.y, e1.z, e1.w};
    const float vv[8] = {v0.x, v0.y, v0.z, v0.w, v1.x, v1.y, v1.z, v1.w};
    short8 ef, vf;
    #pragma unroll
    for (int j = 0; j < 8; ++j) { ef[j] = bf16_rne(ev[j]); vf[j] = bf16_rne(vv[j]); }
    acc = __builtin_amdgcn_mfma_f32_16x16x32_bf16(ef, vf, acc, 0, 0, 0);
    ea += 32; sv += 32;
  }
  // C/D: col=llo -> j (sumf row), row=lhi*4+r -> i (embs row)
  const float invc = scale / (cnts[tj * 16 + llo] + 1e-12f);
  float* lp = logits + (size_t)(ti * 16) * NT + tj * 16 + llo;
  #pragma unroll
  for (int r = 0; r < 4; ++r)
    lp[(size_t)(lhi * 4 + r) * NT] = acc[r] * invc;
}

// K3: LSEs (base-2 internally). Blocks 0..15: col-LSE; 16..31: row-LSE.
__global__ __launch_bounds__(256) void k3_lse(const float* __restrict__ logits,
                                              float* __restrict__ rowlse,
                                              float* __restrict__ clse) {
  const int g = blockIdx.x;
  const int r = threadIdx.x >> 4;
  const int c = threadIdx.x & 15;
  __shared__ float red[16][17];
  if (g < 16) {
    const int col = g * 16 + c;
    float mx = -1e30f;
    #pragma unroll 4
    for (int kk = 0; kk < 16; ++kk)
      mx = fmaxf(mx, logits[(size_t)(kk * 16 + r) * NT + col]);
    red[r][c] = mx; __syncthreads();
    for (int st = 8; st; st >>= 1) { if (r < st) red[r][c] = fmaxf(red[r][c], red[r + st][c]); __syncthreads(); }
    const float mx2 = red[0][c] * LOG2E; __syncthreads();
    float s = 0.f;
    #pragma unroll 4
    for (int kk = 0; kk < 16; ++kk)
      s += exp2f(logits[(size_t)(kk * 16 + r) * NT + col] * LOG2E - mx2);
    red[r][c] = s; __syncthreads();
    for (int st = 8; st; st >>= 1) { if (r < st) red[r][c] += red[r + st][c]; __syncthreads(); }
    if (r == 0) clse[col] = (mx2 + log2f(red[0][c])) * LN2;
  } else {
    const int row = (g - 16) * 16 + r;
    float mx = -1e30f;
    #pragma unroll 4
    for (int kk = 0; kk < 16; ++kk)
      mx = fmaxf(mx, logits[(size_t)row * NT + kk * 16 + c]);
    #pragma unroll
    for (int o = 8; o; o >>= 1) mx = fmaxf(mx, __shfl_xor(mx, o, 64));
    const float mx2 = mx * LOG2E;
    float s = 0.f;
    #pragma unroll 4
    for (int kk = 0; kk < 16; ++kk)
      s += exp2f(logits[(size_t)row * NT + kk * 16 + c] * LOG2E - mx2);
    #pragma unroll
    for (int o = 8; o; o >>= 1) s += __shfl_xor(s, o, 64);
    if (c == 0) rowlse[row] = (mx2 + log2f(s)) * LN2;
  }
}

// K4: final nonzero-avg -> scalar.
__global__ __launch_bounds__(256) void k4_loss(const float* __restrict__ logits,
                                               const float* __restrict__ rowlse,
                                               const float* __restrict__ clse,
                                               const float* __restrict__ cnts,
                                               float* __restrict__ out) {
  const int i = threadIdx.x;
  const float diag = logits[(size_t)i * NT + i];
  const bool valid = cnts[i] > 0.f;
  const float tl = valid ? (rowlse[i] - diag) : 0.f;
  const float pl = valid ? (clse[i] - diag) : 0.f;

  __shared__ float red[4][256];
  red[0][i] = tl;
  red[1][i] = (tl > 0.f) ? 1.f : 0.f;
  red[2][i] = pl;
  red[3][i] = (pl > 0.f) ? 1.f : 0.f;
  __syncthreads();
  for (int st = 128; st > 0; st >>= 1) {
    if (i < st) {
      red[0][i] += red[0][i + st];
      red[1][i] += red[1][i + st];
      red[2][i] += red[2][i + st];
      red[3][i] += red[3][i + st];
    }
    __syncthreads();
  }
  if (i == 0) {
    const float a1 = (red[1][0] > 0.f) ? red[0][0] / fmaxf(red[1][0], 1.f) : 0.f;
    const float a2 = (red[3][0] > 0.f) ? red[2][0] / fmaxf(red[3][0], 1.f) : 0.f;
    out[0] = 0.5f * (a1 + a2);
  }
}

extern "C" void kernel_launch(void* const* d_in, const int* in_sizes, int n_in,
                              void* d_out, int out_size, void* d_ws, size_t ws_size,
                              hipStream_t stream) {
  const float* net  = (const float*)d_in[0];
  const float* embs = (const float*)d_in[1];
  const float* mpts = (const float*)d_in[2];
  const float* lsc  = (const float*)d_in[3];

  float* ws     = (float*)d_ws;
  float* sumf   = ws + OFF_SUMF;
  float* cnts   = ws + OFF_CNTS;
  float* logits = ws + OFF_LOG;
  float* rowlse = ws + OFF_RLSE;
  float* clse   = ws + OFF_CLSE;
  float* outp   = (float*)d_out;

  kz_zero<<<dim3((NZERO / 4 + 255) / 256), dim3(256), 0, stream>>>(ws);
  k1_mfma<<<dim3(BS * KC * DC), dim3(256), 0, stream>>>(net, mpts, sumf, cnts);
  k2_logits<<<dim3(64), dim3(256), 0, stream>>>(embs, sumf, cnts, lsc, logits);
  k3_lse<<<dim3(32), dim3(256), 0, stream>>>(logits, rowlse, clse);
  k4_loss<<<dim3(1), dim3(256), 0, stream>>>(logits, rowlse, clse, cnts, outp);
}

// Round 6
// 52.544 us; speedup vs baseline: 2.8351x; 1.2928x over previous
//
#include <hip/hip_runtime.h>
#include <hip/hip_bf16.h>
#include <math.h>

#define BS 8
#define NPTS 8192
#define NM 32
#define D 512
#define NT (BS*NM)            // 256 masks
#define KC 32                 // K-split factor
#define KCHUNK (NPTS/KC)      // 256 points per block
#define TILES (KCHUNK/32)     // 8 k-tiles of 32
#define DC 8                  // D-chunks
#define DCHUNK (D/DC)         // 64 dims per block (4 waves x 16)
#define NWORDS (NPTS/32)      // 256 uints per mask row

#define LOG2E 1.44269504088896f
#define LN2   0.69314718055995f

typedef short short8 __attribute__((ext_vector_type(8)));
typedef float f32x4 __attribute__((ext_vector_type(4)));

// ws layout (floats):
static constexpr size_t OFF_SUMF = 0;                        // [NT][D] (atomic acc, zeroed by kp)
static constexpr size_t OFF_CNTS = OFF_SUMF + (size_t)NT*D;  // [NT]
static constexpr size_t OFF_BITS = OFF_CNTS + NT;            // [NT][NWORDS] uints = 256KB
static constexpr size_t OFF_LOG  = OFF_BITS + (size_t)NT*NWORDS;
static constexpr size_t OFF_RLSE = OFF_LOG + (size_t)NT*NT;
static constexpr size_t OFF_CLSE = OFF_RLSE + NT;

__device__ __forceinline__ short bf16_rne(float f) {
  return __builtin_bit_cast(short, __float2bfloat16(f));
}

#define GLOAD_LDS16(g, l) __builtin_amdgcn_global_load_lds( \
    (const __attribute__((address_space(1))) void*)(g),     \
    (__attribute__((address_space(3))) void*)(l), 16, 0, 0)

// KP: bit-pack mask (8MB f32 -> 256KB bits), exact popcount counts, zero sumf.
// Grid: 256 blocks (one per mask), 256 threads.
__global__ __launch_bounds__(256) void kp_prep(const float* __restrict__ mpts,
                                               unsigned int* __restrict__ mbits,
                                               float* __restrict__ cnts,
                                               float* __restrict__ sumf) {
  const int n = blockIdx.x;
  const int t = threadIdx.x;

  // thread t packs points [t*32, t*32+32) -> one uint
  const float4* mp = (const float4*)(mpts + ((size_t)n << 13) + t * 32);
  unsigned int u = 0;
  #pragma unroll
  for (int q = 0; q < 8; ++q) {
    const float4 v = mp[q];
    u |= (v.x != 0.f ? 1u : 0u) << (q * 4 + 0);
    u |= (v.y != 0.f ? 1u : 0u) << (q * 4 + 1);
    u |= (v.z != 0.f ? 1u : 0u) << (q * 4 + 2);
    u |= (v.w != 0.f ? 1u : 0u) << (q * 4 + 3);
  }
  mbits[n * NWORDS + t] = u;

  // zero this mask's sumf row (512 floats / 256 threads = float2 each)
  ((float2*)(sumf + ((size_t)n << 9)))[t] = make_float2(0.f, 0.f);

  // exact count via popcount reduce
  int c = __popc(u);
  #pragma unroll
  for (int o = 32; o > 0; o >>= 1) c += __shfl_down(c, o, 64);
  __shared__ int red[4];
  if ((t & 63) == 0) red[t >> 6] = c;
  __syncthreads();
  if (t == 0) cnts[n] = (float)(red[0] + red[1] + red[2] + red[3]);
}

// K1: masked-sum einsum via bf16 MFMA; net staged by global_load_lds
// (XOR-swizzled granules), mask A-operand unpacked from the bit matrix.
// Grid: b(8) x kc(32) x dc(8) = 2048 blocks -> 8 blocks/CU.
__global__ __launch_bounds__(256, 8) void k1_mfma(const float* __restrict__ net,
                                                  const unsigned int* __restrict__ mbits,
                                                  float* __restrict__ sumf) {
  __shared__ float tile[2][32 * DCHUNK];   // 8KB per buffer
  const int bx = blockIdx.x;
  const int dc = bx & 7;
  const int kc = (bx >> 3) & 31;
  const int b  = bx >> 8;
  const int w    = threadIdx.x >> 6;
  const int lane = threadIdx.x & 63;
  const int lhi = lane >> 4, llo = lane & 15;
  const int k0 = kc * KCHUNK;

  // stage k-tile t; dest lane-linear, global src granule pre-swizzled
  auto stage = [&](int buf, int t) {
    const int kt = k0 + t * 32;
    #pragma unroll
    for (int si = 0; si < 2; ++si) {
      const int s = w * 2 + si;
      const int gsrc = (lane & 15) ^ (((s >> 1) & 3) << 2);
      const float* src = net
        + (((size_t)(b * NPTS + kt + s * 4 + (lane >> 4))) << 9)
        + dc * DCHUNK + (gsrc << 2);
      GLOAD_LDS16(src, &tile[buf][s * 256]);
    }
  };

  // A bit rows: mask rows llo and llo+16, uint index kc*8 + t
  const unsigned int* r0 = mbits + (size_t)(b * NM + llo) * NWORDS + kc * TILES;
  const unsigned int* r1 = r0 + (size_t)16 * NWORDS;

  f32x4 acc0 = {0.f, 0.f, 0.f, 0.f};
  f32x4 acc1 = {0.f, 0.f, 0.f, 0.f};

  // swizzled LDS read base (2-way max bank aliasing = free)
  const int rbase = (lhi * 8) * 64 + ((((w * 4) + (llo >> 2)) ^ (lhi << 2)) << 2) + (llo & 3);
  const int sh = lhi * 8;

  stage(0, 0);
  __syncthreads();

  #pragma unroll
  for (int t = 0; t < TILES; ++t) {
    const int cur = t & 1;
    const unsigned int u0 = r0[t];
    const unsigned int u1 = r1[t];
    if (t + 1 < TILES) stage(cur ^ 1, t + 1);

    float bv[8];
    #pragma unroll
    for (int j = 0; j < 8; ++j) bv[j] = tile[cur][rbase + j * 64];

    short8 bf, a0f, a1f;
    #pragma unroll
    for (int j = 0; j < 8; ++j) bf[j] = bf16_rne(bv[j]);
    const unsigned int b0 = (u0 >> sh) & 0xffu;
    const unsigned int b1 = (u1 >> sh) & 0xffu;
    #pragma unroll
    for (int j = 0; j < 8; ++j) {
      a0f[j] = (short)(-(int)((b0 >> j) & 1u) & 0x3F80);
      a1f[j] = (short)(-(int)((b1 >> j) & 1u) & 0x3F80);
    }

    acc0 = __builtin_amdgcn_mfma_f32_16x16x32_bf16(a0f, bf, acc0, 0, 0, 0);
    acc1 = __builtin_amdgcn_mfma_f32_16x16x32_bf16(a1f, bf, acc1, 0, 0, 0);

    __syncthreads();
  }

  // C/D: col = llo (d), row = lhi*4 + j (m) [m89-verified]; atomic accumulate
  const int d0 = dc * DCHUNK + w * 16;
  float* sp = sumf + (((size_t)(b * NM)) << 9) + d0 + llo;
  #pragma unroll
  for (int j = 0; j < 4; ++j) {
    atomicAdd(sp + ((size_t)(lhi * 4 + j) << 9),      acc0[j]);
    atomicAdd(sp + ((size_t)(16 + lhi * 4 + j) << 9), acc1[j]);
  }
}

// K2: logits = exp(lsc) * (embs @ sumf^T) * inv_cnt[col], bf16 MFMA.
// Grid: 256 blocks x 1 wave = one 16x16 tile each.
__global__ __launch_bounds__(64) void k2_logits(const float* __restrict__ embs,
                                                const float* __restrict__ sumf,
                                                const float* __restrict__ cnts,
                                                const float* __restrict__ lsc,
                                                float* __restrict__ logits) {
  const int lane = threadIdx.x;
  const int wt = blockIdx.x;                // 0..255
  const int ti = wt >> 4, tj = wt & 15;
  const int lhi = lane >> 4, llo = lane & 15;
  const float scale = expf(lsc[0]);

  const float* ea = embs + (((size_t)(ti * 16 + llo)) << 9) + lhi * 8;
  const float* sv = sumf + (((size_t)(tj * 16 + llo)) << 9) + lhi * 8;
  f32x4 acc = {0.f, 0.f, 0.f, 0.f};
  #pragma unroll 4
  for (int kk = 0; kk < D / 32; ++kk) {
    const float4 e0 = *(const float4*)(ea);
    const float4 e1 = *(const float4*)(ea + 4);
    const float4 v0 = *(const float4*)(sv);
    const float4 v1 = *(const float4*)(sv + 4);
    const float ev[8] = {e0.x, e0.y, e0.z, e0.w, e1.x, e1.y, e1.z, e1.w};
    const float vv[8] = {v0.x, v0.y, v0.z, v0.w, v1.x, v1.y, v1.z, v1.w};
    short8 ef, vf;
    #pragma unroll
    for (int j = 0; j < 8; ++j) { ef[j] = bf16_rne(ev[j]); vf[j] = bf16_rne(vv[j]); }
    acc = __builtin_amdgcn_mfma_f32_16x16x32_bf16(ef, vf, acc, 0, 0, 0);
    ea += 32; sv += 32;
  }
  const float invc = scale / (cnts[tj * 16 + llo] + 1e-12f);
  float* lp = logits + (size_t)(ti * 16) * NT + tj * 16 + llo;
  #pragma unroll
  for (int r = 0; r < 4; ++r)
    lp[(size_t)(lhi * 4 + r) * NT] = acc[r] * invc;
}

// K3: LSEs (base-2). Blocks 0..15: col-LSE; 16..31: row-LSE.
__global__ __launch_bounds__(256) void k3_lse(const float* __restrict__ logits,
                                              float* __restrict__ rowlse,
                                              float* __restrict__ clse) {
  const int g = blockIdx.x;
  const int r = threadIdx.x >> 4;
  const int c = threadIdx.x & 15;
  __shared__ float red[16][17];
  if (g < 16) {
    const int col = g * 16 + c;
    float mx = -1e30f;
    #pragma unroll 4
    for (int kk = 0; kk < 16; ++kk)
      mx = fmaxf(mx, logits[(size_t)(kk * 16 + r) * NT + col]);
    red[r][c] = mx; __syncthreads();
    for (int st = 8; st; st >>= 1) { if (r < st) red[r][c] = fmaxf(red[r][c], red[r + st][c]); __syncthreads(); }
    const float mx2 = red[0][c] * LOG2E; __syncthreads();
    float s = 0.f;
    #pragma unroll 4
    for (int kk = 0; kk < 16; ++kk)
      s += exp2f(logits[(size_t)(kk * 16 + r) * NT + col] * LOG2E - mx2);
    red[r][c] = s; __syncthreads();
    for (int st = 8; st; st >>= 1) { if (r < st) red[r][c] += red[r + st][c]; __syncthreads(); }
    if (r == 0) clse[col] = (mx2 + log2f(red[0][c])) * LN2;
  } else {
    const int row = (g - 16) * 16 + r;
    float mx = -1e30f;
    #pragma unroll 4
    for (int kk = 0; kk < 16; ++kk)
      mx = fmaxf(mx, logits[(size_t)row * NT + kk * 16 + c]);
    #pragma unroll
    for (int o = 8; o; o >>= 1) mx = fmaxf(mx, __shfl_xor(mx, o, 64));
    const float mx2 = mx * LOG2E;
    float s = 0.f;
    #pragma unroll 4
    for (int kk = 0; kk < 16; ++kk)
      s += exp2f(logits[(size_t)row * NT + kk * 16 + c] * LOG2E - mx2);
    #pragma unroll
    for (int o = 8; o; o >>= 1) s += __shfl_xor(s, o, 64);
    if (c == 0) rowlse[row] = (mx2 + log2f(s)) * LN2;
  }
}

// K4: final nonzero-avg -> scalar.
__global__ __launch_bounds__(256) void k4_loss(const float* __restrict__ logits,
                                               const float* __restrict__ rowlse,
                                               const float* __restrict__ clse,
                                               const float* __restrict__ cnts,
                                               float* __restrict__ out) {
  const int i = threadIdx.x;
  const float diag = logits[(size_t)i * NT + i];
  const bool valid = cnts[i] > 0.f;
  const float tl = valid ? (rowlse[i] - diag) : 0.f;
  const float pl = valid ? (clse[i] - diag) : 0.f;

  __shared__ float red[4][256];
  red[0][i] = tl;
  red[1][i] = (tl > 0.f) ? 1.f : 0.f;
  red[2][i] = pl;
  red[3][i] = (pl > 0.f) ? 1.f : 0.f;
  __syncthreads();
  for (int st = 128; st > 0; st >>= 1) {
    if (i < st) {
      red[0][i] += red[0][i + st];
      red[1][i] += red[1][i + st];
      red[2][i] += red[2][i + st];
      red[3][i] += red[3][i + st];
    }
    __syncthreads();
  }
  if (i == 0) {
    const float a1 = (red[1][0] > 0.f) ? red[0][0] / fmaxf(red[1][0], 1.f) : 0.f;
    const float a2 = (red[3][0] > 0.f) ? red[2][0] / fmaxf(red[3][0], 1.f) : 0.f;
    out[0] = 0.5f * (a1 + a2);
  }
}

extern "C" void kernel_launch(void* const* d_in, const int* in_sizes, int n_in,
                              void* d_out, int out_size, void* d_ws, size_t ws_size,
                              hipStream_t stream) {
  const float* net  = (const float*)d_in[0];
  const float* embs = (const float*)d_in[1];
  const float* mpts = (const float*)d_in[2];
  const float* lsc  = (const float*)d_in[3];

  float* ws     = (float*)d_ws;
  float* sumf   = ws + OFF_SUMF;
  float* cnts   = ws + OFF_CNTS;
  unsigned int* mbits = (unsigned int*)(ws + OFF_BITS);
  float* logits = ws + OFF_LOG;
  float* rowlse = ws + OFF_RLSE;
  float* clse   = ws + OFF_CLSE;
  float* outp   = (float*)d_out;

  kp_prep<<<dim3(NT), dim3(256), 0, stream>>>(mpts, mbits, cnts, sumf);
  k1_mfma<<<dim3(BS * KC * DC), dim3(256), 0, stream>>>(net, mbits, sumf);
  k2_logits<<<dim3(NT), dim3(64), 0, stream>>>(embs, sumf, cnts, lsc, logits);
  k3_lse<<<dim3(32), dim3(256), 0, stream>>>(logits, rowlse, clse);
  k4_loss<<<dim3(1), dim3(256), 0, stream>>>(logits, rowlse, clse, cnts, outp);
}